// Round 5
// baseline (143.234 us; speedup 1.0000x reference)
//
#include <hip/hip_runtime.h>
#include <hip/hip_bf16.h>
#include <math.h>

#define B_    4
#define CIN   128
#define L_    16384
#define NH    4
#define NN    32
#define MT    528
#define CP    2112
#define DIM_  64
#define LT    64
#define MID   8192
#define EPS_  1e-5f

// padded-K layout: 80 K-chunks of 32; within each chunk, quad (k>>3) == head.
#define KPH   640
#define KTOT  2560
#define WSWN  (KTOT * DIM_)       // 163840 fp16 slots
#define FSWN  (2 * 4 * 64 * 8)    // 4096 fp16 slots
#define LOGITS_BLOCKS 1024
#define PREP_BLOCKS   656         // (WSWN+FSWN)/256

typedef __attribute__((ext_vector_type(8))) short short8;
typedef __attribute__((ext_vector_type(4))) float float4v;
typedef __attribute__((ext_vector_type(4))) unsigned uint4v;
typedef __attribute__((ext_vector_type(2))) _Float16 h2;
typedef __attribute__((ext_vector_type(8))) _Float16 half8;

__device__ inline unsigned short f2h(float f) {
  _Float16 h = (_Float16)f;              // RNE
  return __builtin_bit_cast(unsigned short, h);
}

__device__ inline h2 pkrtz(float a, float b) {
  return __builtin_bit_cast(h2, __builtin_amdgcn_cvt_pkrtz(a, b));
}

// decode head-local k-block (0..79) -> (i, jb)
__device__ inline void kb_decode(int id, int& i, int& jb) {
  if (id < 32)      { i = id >> 2;               jb = id & 3; }
  else if (id < 56) { int r = id - 32; int d = r / 3; i = 8 + d;  jb = 1 + (r - 3 * d); }
  else if (id < 72) { int r = id - 56; i = 16 + (r >> 1); jb = 2 + (r & 1); }
  else              { i = 24 + (id - 72);         jb = 3; }
}

// ---------------- kernel 1: logits (closed-form) ∪ weight-swizzle prep ----------------
__global__ __launch_bounds__(256) void k_pre(const float* __restrict__ dr_w,
                                             const float* __restrict__ fc1_w,
                                             const float* __restrict__ x,
                                             const float* __restrict__ g1,
                                             const float* __restrict__ b1,
                                             unsigned short* __restrict__ wsw,
                                             unsigned short* __restrict__ fsw,
                                             float* __restrict__ ws_a,
                                             float* __restrict__ ws_bsum) {
  if (blockIdx.x >= LOGITS_BLOCKS) {
    // ---- prep path: swizzle dr_w / fc1_w into MFMA A-frag order (fp16) ----
    // K-order: chunk g = s>>11 (0..79); quad (lane>>4) == head; head-local k = g*8 + j.
    int s = (blockIdx.x - LOGITS_BLOCKS) * 256 + threadIdx.x;
    if (s < WSWN) {
      int j    = s & 7;
      int lane = (s >> 3) & 63;
      int ot   = (s >> 9) & 3;
      int ksg  = s >> 11;              // K-chunk 0..79
      int o  = ot * 16 + (lane & 15);
      int h  = lane >> 4;              // quad == head
      int i, jb; kb_decode(ksg, i, jb);
      int jch = jb * 8 + j;
      float val = 0.f;
      if (jch >= i) {
        int fi = 32 * i - (i * (i - 1)) / 2;
        int m  = h * MT + fi + (jch - i);
        val = dr_w[(size_t)o * CP + m];
      }
      wsw[s] = f2h(val);
    } else {
      int s2 = s - WSWN;
      int j    = s2 & 7;
      int lane = (s2 >> 3) & 63;
      int ot   = (s2 >> 9) & 3;
      int ks2  = s2 >> 11;
      int o = ot * 16 + (lane & 15);
      int c = ks2 * 32 + (lane >> 4) * 8 + j;
      fsw[s2] = f2h(fc1_w[o * DIM_ + c]);
    }
    return;
  }
  // ---- logits path ----
  int blk = blockIdx.x;
  int b = blk >> 8;
  int l0 = (blk & 255) << 6;
  int t = threadIdx.x;
  int l = t & 63, q = t >> 6;
  __shared__ float xs[CIN], smid[CIN];
  __shared__ float part[4][64], part2[4][64], mu_s[64], isd_s[64];
  __shared__ float musd[2];

  if (t < CIN) xs[t] = x[(size_t)b * CIN * L_ + (size_t)t * L_ + MID];

  float tv[32];
  const float* xb = x + (size_t)b * CIN * L_ + l0 + l;
  float s = 0.f, s2 = 0.f;
#pragma unroll
  for (int cc = 0; cc < 32; cc++) {
    float v = xb[(size_t)(cc * 4 + q) * L_];
    tv[cc] = v; s += v; s2 += v * v;
  }
  part[q][l] = s; part2[q][l] = s2;
  __syncthreads();
  if (t < 64) {
    // MID-column LN stats via wave-0 butterfly
    float a = xs[t], bb = xs[t + 64];
    float ms = a + bb, ms2 = a * a + bb * bb;
#pragma unroll
    for (int mk = 1; mk < 64; mk <<= 1) {
      ms += __shfl_xor(ms, mk, 64);
      ms2 += __shfl_xor(ms2, mk, 64);
    }
    if (t == 0) {
      float mu = ms * (1.f / CIN);
      musd[0] = mu;
      musd[1] = rsqrtf(ms2 * (1.f / CIN) - mu * mu + EPS_);
    }
    // per-position LN stats
    float su = part[0][t] + part[1][t] + part[2][t] + part[3][t];
    float su2 = part2[0][t] + part2[1][t] + part2[2][t] + part2[3][t];
    float mu = su * (1.f / CIN);
    float var = su2 * (1.f / CIN) - mu * mu;
    mu_s[t] = mu; isd_s[t] = rsqrtf(var + EPS_);
  }
  __syncthreads();
  if (t < CIN) {
    int c = ((t & 31) << 2) + (t >> 5);   // shuffled row -> orig channel
    smid[t] = (xs[c] - musd[0]) * musd[1] * g1[c] + b1[c];
  }
  {
    float mu = mu_s[l], isd = isd_s[l];
#pragma unroll
    for (int cc = 0; cc < 32; cc++) {
      int co = cc * 4 + q;
      tv[cc] = (tv[cc] - mu) * isd * g1[co] + b1[co];
    }
  }
  __syncthreads();
  float T2 = 0.f, T4 = 0.f, st = 0.f, sc2 = 0.f, S2 = 0.f, S4 = 0.f;
#pragma unroll
  for (int i = 0; i < 32; i++) {
    float si = smid[q * 32 + i];
    float ti = tv[i];
    float t2 = ti * ti;
    T2 += t2; T4 = fmaf(t2, t2, T4);
    float ci = si * ti;
    st += ci; sc2 = fmaf(ci, ci, sc2);
    float s2i = si * si;
    S2 += s2i; S4 = fmaf(s2i, s2i, S4);
  }
  float num = 0.5f * (st * st + sc2);
  float logit = num * rsqrtf(0.25f * (T2 * T2 + T4) * (S2 * S2 + S4));
  float e = expf(logit - 1.f);
  ws_a[((size_t)b * NH + q) * L_ + l0 + l] = e;
  float ws = e;
#pragma unroll
  for (int mk = 1; mk < 64; mk <<= 1) ws += __shfl_xor(ws, mk, 64);
  if (l == 0) ws_bsum[((size_t)b * NH + q) * 256 + (blk & 255)] = ws;
}

// ---------------- kernel 2: MFMA main — fp16 pk-mul P-build, 8 phases x 10 chunks ----------------
struct __align__(16) SmemM {
  union __align__(16) { unsigned short p2[4 * 10 * 4 * 16 * 8]; float zb[64 * 65]; } u1; // 40960 B
  unsigned short zn2[4 * 2 * 4 * 16 * 8];   // 8192 B
  float part[4][64], part2[4][64], mu_s[64], isd_s[64];
};

__global__ __launch_bounds__(256) void k_main(const float* __restrict__ x,
      const float* __restrict__ g1, const float* __restrict__ b1,
      const float* __restrict__ dr_b,
      const float* __restrict__ g2, const float* __restrict__ b2,
      const float* __restrict__ fc1_b,
      const unsigned short* __restrict__ wsw, const unsigned short* __restrict__ fsw,
      const float* __restrict__ ws_a, const float* __restrict__ ws_bsum,
      float* __restrict__ out) {
  __shared__ SmemM sm;
  int blk = blockIdx.x;
  int b = blk >> 8;
  int l0 = (blk & 255) << 6;
  int t = threadIdx.x;
  int l = t & 63, q = t >> 6;

  // asum: parallel 256-partial read + wave butterfly
  float asum;
  {
    const float* bs = ws_bsum + ((size_t)b * NH + q) * 256;
    float a0 = bs[l] + bs[l + 64] + bs[l + 128] + bs[l + 192];
#pragma unroll
    for (int mk = 1; mk < 64; mk <<= 1) a0 += __shfl_xor(a0, mk, 64);
    asum = a0;
  }
  float e = ws_a[((size_t)b * NH + q) * L_ + l0 + l];
  float sa = sqrtf(e * ((float)L_ / asum));

  // staging: thread (l,q) holds head q's 32 shuffled channels at position l0+l,
  // packed as 16 fp16-pair registers (shuffled row 32q+cc <-> orig channel cc*4+q).
  const float* xb = x + (size_t)b * CIN * L_ + l0 + l;
  h2 tnh[16];
  float s = 0.f, s2 = 0.f;
#pragma unroll
  for (int r = 0; r < 16; r++) {
    float v0 = xb[(size_t)((2 * r) * 4 + q) * L_];
    float v1 = xb[(size_t)((2 * r + 1) * 4 + q) * L_];
    s += v0 + v1; s2 += v0 * v0 + v1 * v1;
    tnh[r] = pkrtz(v0, v1);
  }
  sm.part[q][l] = s; sm.part2[q][l] = s2;
  __syncthreads();
  if (t < 64) {
    float su = sm.part[0][t] + sm.part[1][t] + sm.part[2][t] + sm.part[3][t];
    float su2 = sm.part2[0][t] + sm.part2[1][t] + sm.part2[2][t] + sm.part2[3][t];
    float mu = su * (1.f / CIN);
    float var = su2 * (1.f / CIN) - mu * mu;
    sm.mu_s[t] = mu; sm.isd_s[t] = rsqrtf(var + EPS_);
  }
  __syncthreads();
  {
    float mu = sm.mu_s[l], isd = sm.isd_s[l];
#pragma unroll
    for (int r = 0; r < 16; r++) {
      int c0 = (2 * r) * 4 + q, c1 = c0 + 4;
      float v0 = ((float)tnh[r][0] - mu) * isd * g1[c0] + b1[c0];
      float v1 = ((float)tnh[r][1] - mu) * isd * g1[c1] + b1[c1];
      v0 *= sa; v1 *= sa;
      tnh[r] = pkrtz(v0, v1);
    }
  }

  // main GEMM: wave q owns otile-pair (q&1) x ltile-pair (q>>1)
  const int otp = q & 1, ltp = q >> 1;
  const int lta = ltp * 2, ltb = ltp * 2 + 1;
  float4v acc[2][2];
  acc[0][0] = (float4v)0.f; acc[0][1] = (float4v)0.f;
  acc[1][0] = (float4v)0.f; acc[1][1] = (float4v)0.f;
  int tl = l;
  int ltile = l >> 4, n = l & 15;

  // 8 phases x 10 chunks; fully unrolled so all tnh[] indices are compile-time
#pragma unroll
  for (int p = 0; p < 8; p++) {
    // P-build: thread (l,q) builds its OWN head's blocks via packed fp16 muls.
#pragma unroll
    for (int ks = 0; ks < 10; ks++) {
      const int g = p * 10 + ks;           // global K-chunk == head-local k-block
      int i, jb; kb_decode(g, i, jb);
      _Float16 uh = tnh[i >> 1][i & 1];
      h2 uu = {uh, uh};
      h2 p0 = uu * tnh[jb * 4 + 0];
      h2 p1 = uu * tnh[jb * 4 + 1];
      h2 p2v = uu * tnh[jb * 4 + 2];
      h2 p3 = uu * tnh[jb * 4 + 3];
      uint4v pv = {__builtin_bit_cast(unsigned, p0), __builtin_bit_cast(unsigned, p1),
                   __builtin_bit_cast(unsigned, p2v), __builtin_bit_cast(unsigned, p3)};
      *(uint4v*)&sm.u1.p2[(((ltile * 10 + ks) * 4 + q) * 16 + n) * 8] = pv;
    }
    __syncthreads();
    // consume: 2 otiles x 2 ltiles per wave
#pragma unroll
    for (int ks = 0; ks < 10; ks++) {
      const unsigned short* wk = wsw + (size_t)(p * 10 + ks) * 2048 + otp * 1024 + tl * 8;
      half8 a0 = *(const half8*)(wk);
      half8 a1 = *(const half8*)(wk + 512);
      half8 b0 = *(half8*)&sm.u1.p2[((lta * 10 + ks) * 64 + tl) * 8];
      half8 b1v = *(half8*)&sm.u1.p2[((ltb * 10 + ks) * 64 + tl) * 8];
      acc[0][0] = __builtin_amdgcn_mfma_f32_16x16x32_f16(a0, b0,  acc[0][0], 0, 0, 0);
      acc[0][1] = __builtin_amdgcn_mfma_f32_16x16x32_f16(a0, b1v, acc[0][1], 0, 0, 0);
      acc[1][0] = __builtin_amdgcn_mfma_f32_16x16x32_f16(a1, b0,  acc[1][0], 0, 0, 0);
      acc[1][1] = __builtin_amdgcn_mfma_f32_16x16x32_f16(a1, b1v, acc[1][1], 0, 0, 0);
    }
    __syncthreads();
  }

  // epilogue: z -> zb (2x2 mapping), norm2, zn2 frags, fc1 MFMA, GELU
  int quad = tl >> 4;
#pragma unroll
  for (int oi = 0; oi < 2; oi++) {
#pragma unroll
    for (int li = 0; li < 2; li++) {
      int ot = otp * 2 + oi, ltx = ltp * 2 + li;
#pragma unroll
      for (int r = 0; r < 4; r++) {
        int o = ot * 16 + quad * 4 + r;
        sm.u1.zb[(ltx * 16 + n) * 65 + o] = acc[oi][li][r] + dr_b[o];
      }
    }
  }
  __syncthreads();
  {
    float ss = 0.f, ss2 = 0.f;
#pragma unroll
    for (int k = 0; k < 16; k++) {
      float v = sm.u1.zb[l * 65 + q * 16 + k];
      ss += v; ss2 += v * v;
    }
    sm.part[q][l] = ss; sm.part2[q][l] = ss2;
  }
  __syncthreads();
  if (t < 64) {
    float su = sm.part[0][t] + sm.part[1][t] + sm.part[2][t] + sm.part[3][t];
    float su2 = sm.part2[0][t] + sm.part2[1][t] + sm.part2[2][t] + sm.part2[3][t];
    float mu = su * (1.f / DIM_);
    float var = su2 * (1.f / DIM_) - mu * mu;
    sm.mu_s[t] = mu; sm.isd_s[t] = rsqrtf(var + EPS_);
  }
  __syncthreads();
  {
    float mu2 = sm.mu_s[l], isd2 = sm.isd_s[l];
#pragma unroll
    for (int kk = 0; kk < 2; kk++) {
      int kb2 = q * 2 + kk;
      int c0 = kb2 * 8;
      unsigned short pk[8];
#pragma unroll
      for (int e8 = 0; e8 < 8; e8++) {
        int c = c0 + e8;
        float v = (sm.u1.zb[l * 65 + c] - mu2) * isd2 * g2[c] + b2[c];
        pk[e8] = f2h(v);
      }
      int ks2 = kb2 >> 2, qd2 = kb2 & 3;
      *(short8*)&sm.zn2[(((ltile * 2 + ks2) * 4 + qd2) * 16 + n) * 8] = *(short8*)pk;
    }
  }
  __syncthreads();
  float4v acc2[4];
  acc2[0] = (float4v)0.f; acc2[1] = (float4v)0.f; acc2[2] = (float4v)0.f; acc2[3] = (float4v)0.f;
#pragma unroll
  for (int ks2 = 0; ks2 < 2; ks2++) {
    half8 bz = *(half8*)&sm.zn2[((q * 2 + ks2) * 64 + tl) * 8];
    const unsigned short* fk = fsw + ks2 * 2048 + tl * 8;
    half8 f0 = *(const half8*)(fk);
    half8 f1 = *(const half8*)(fk + 512);
    half8 f2 = *(const half8*)(fk + 1024);
    half8 f3 = *(const half8*)(fk + 1536);
    acc2[0] = __builtin_amdgcn_mfma_f32_16x16x32_f16(f0, bz, acc2[0], 0, 0, 0);
    acc2[1] = __builtin_amdgcn_mfma_f32_16x16x32_f16(f1, bz, acc2[1], 0, 0, 0);
    acc2[2] = __builtin_amdgcn_mfma_f32_16x16x32_f16(f2, bz, acc2[2], 0, 0, 0);
    acc2[3] = __builtin_amdgcn_mfma_f32_16x16x32_f16(f3, bz, acc2[3], 0, 0, 0);
  }
#pragma unroll
  for (int ot = 0; ot < 4; ot++) {
#pragma unroll
    for (int r = 0; r < 4; r++) {
      int o2 = ot * 16 + quad * 4 + r;
      float sv = acc2[ot][r] + fc1_b[o2];
      float g = 0.5f * sv * (1.f + erff(sv * 0.70710678118f));
      out[((size_t)b * DIM_ + o2) * L_ + l0 + q * 16 + n] = g;
    }
  }
}

extern "C" void kernel_launch(void* const* d_in, const int* in_sizes, int n_in,
                              void* d_out, int out_size, void* d_ws, size_t ws_size,
                              hipStream_t stream) {
  const float* x    = (const float*)d_in[0];
  const float* n1w  = (const float*)d_in[1];
  const float* n1b  = (const float*)d_in[2];
  const float* drw  = (const float*)d_in[3];
  const float* drb  = (const float*)d_in[4];
  const float* n2w  = (const float*)d_in[5];
  const float* n2b  = (const float*)d_in[6];
  const float* fc1w = (const float*)d_in[7];
  const float* fc1b = (const float*)d_in[8];
  float* out = (float*)d_out;
  float* ws = (float*)d_ws;
  float* ws_a    = ws;                                  // 4*4*16384 floats
  float* ws_bsum = ws_a + (size_t)B_ * NH * L_;         // 16*256 floats
  unsigned short* wsw = (unsigned short*)(ws_bsum + B_ * NH * 256); // 163840 fp16
  unsigned short* fsw = wsw + WSWN;                     // 4096 fp16

  hipLaunchKernelGGL(k_pre, dim3(LOGITS_BLOCKS + PREP_BLOCKS), dim3(256), 0, stream,
                     drw, fc1w, x, n1w, n1b, wsw, fsw, ws_a, ws_bsum);
  hipLaunchKernelGGL(k_main, dim3(B_ * (L_ / LT)), dim3(256), 0, stream,
                     x, n1w, n1b, drb, n2w, n2b, fc1b, wsw, fsw, ws_a, ws_bsum, out);
}

// Round 6
// 128.336 us; speedup vs baseline: 1.1161x; 1.1161x over previous
//
#include <hip/hip_runtime.h>
#include <hip/hip_bf16.h>
#include <math.h>

#define B_    4
#define CIN   128
#define L_    16384
#define NH    4
#define NN    32
#define MT    528
#define CP    2112
#define DIM_  64
#define LT    64
#define MID   8192
#define EPS_  1e-5f

// padded-K layout: 80 K-chunks of 32; within each chunk, quad (k>>3) == head.
#define KPH   640
#define KTOT  2560
#define WSWN  (KTOT * DIM_)       // 163840 fp16 slots
#define FSWN  (2 * 4 * 64 * 8)    // 4096 fp16 slots
#define LOGITS_BLOCKS 1024
#define PREP_BLOCKS   656         // (WSWN+FSWN)/256

typedef __attribute__((ext_vector_type(8))) short short8;
typedef __attribute__((ext_vector_type(4))) float float4v;
typedef __attribute__((ext_vector_type(4))) unsigned uint4v;
typedef __attribute__((ext_vector_type(2))) _Float16 h2;
typedef __attribute__((ext_vector_type(8))) _Float16 half8;

__device__ inline unsigned short f2h(float f) {
  _Float16 h = (_Float16)f;              // RNE
  return __builtin_bit_cast(unsigned short, h);
}

__device__ inline h2 pkrtz(float a, float b) {
  return __builtin_bit_cast(h2, __builtin_amdgcn_cvt_pkrtz(a, b));
}

// decode head-local k-block (0..79) -> (i, jb)
__device__ inline void kb_decode(int id, int& i, int& jb) {
  if (id < 32)      { i = id >> 2;               jb = id & 3; }
  else if (id < 56) { int r = id - 32; int d = r / 3; i = 8 + d;  jb = 1 + (r - 3 * d); }
  else if (id < 72) { int r = id - 56; i = 16 + (r >> 1); jb = 2 + (r & 1); }
  else              { i = 24 + (id - 72);         jb = 3; }
}

// ---------------- kernel 1: logits (closed-form) ∪ weight-swizzle prep ----------------
__global__ __launch_bounds__(256) void k_pre(const float* __restrict__ dr_w,
                                             const float* __restrict__ fc1_w,
                                             const float* __restrict__ x,
                                             const float* __restrict__ g1,
                                             const float* __restrict__ b1,
                                             unsigned short* __restrict__ wsw,
                                             unsigned short* __restrict__ fsw,
                                             float* __restrict__ ws_a,
                                             float* __restrict__ ws_bsum) {
  if (blockIdx.x >= LOGITS_BLOCKS) {
    // ---- prep path: swizzle dr_w / fc1_w into MFMA A-frag order (fp16) ----
    // K-order: chunk g = s>>11 (0..79); quad (lane>>4) == head; head-local k = g*8 + j.
    int s = (blockIdx.x - LOGITS_BLOCKS) * 256 + threadIdx.x;
    if (s < WSWN) {
      int j    = s & 7;
      int lane = (s >> 3) & 63;
      int ot   = (s >> 9) & 3;
      int ksg  = s >> 11;              // K-chunk 0..79
      int o  = ot * 16 + (lane & 15);
      int h  = lane >> 4;              // quad == head
      int i, jb; kb_decode(ksg, i, jb);
      int jch = jb * 8 + j;
      float val = 0.f;
      if (jch >= i) {
        int fi = 32 * i - (i * (i - 1)) / 2;
        int m  = h * MT + fi + (jch - i);
        val = dr_w[(size_t)o * CP + m];
      }
      wsw[s] = f2h(val);
    } else {
      int s2 = s - WSWN;
      int j    = s2 & 7;
      int lane = (s2 >> 3) & 63;
      int ot   = (s2 >> 9) & 3;
      int ks2  = s2 >> 11;
      int o = ot * 16 + (lane & 15);
      int c = ks2 * 32 + (lane >> 4) * 8 + j;
      fsw[s2] = f2h(fc1_w[o * DIM_ + c]);
    }
    return;
  }
  // ---- logits path ----
  int blk = blockIdx.x;
  int b = blk >> 8;
  int l0 = (blk & 255) << 6;
  int t = threadIdx.x;
  int l = t & 63, q = t >> 6;
  __shared__ float xs[CIN], smid[CIN];
  __shared__ float part[4][64], part2[4][64], mu_s[64], isd_s[64];
  __shared__ float musd[2];

  if (t < CIN) xs[t] = x[(size_t)b * CIN * L_ + (size_t)t * L_ + MID];

  float tv[32];
  const float* xb = x + (size_t)b * CIN * L_ + l0 + l;
  float s = 0.f, s2 = 0.f;
#pragma unroll
  for (int cc = 0; cc < 32; cc++) {
    float v = xb[(size_t)(cc * 4 + q) * L_];
    tv[cc] = v; s += v; s2 += v * v;
  }
  part[q][l] = s; part2[q][l] = s2;
  __syncthreads();
  if (t < 64) {
    // MID-column LN stats via wave-0 butterfly
    float a = xs[t], bb = xs[t + 64];
    float ms = a + bb, ms2 = a * a + bb * bb;
#pragma unroll
    for (int mk = 1; mk < 64; mk <<= 1) {
      ms += __shfl_xor(ms, mk, 64);
      ms2 += __shfl_xor(ms2, mk, 64);
    }
    if (t == 0) {
      float mu = ms * (1.f / CIN);
      musd[0] = mu;
      musd[1] = rsqrtf(ms2 * (1.f / CIN) - mu * mu + EPS_);
    }
    // per-position LN stats
    float su = part[0][t] + part[1][t] + part[2][t] + part[3][t];
    float su2 = part2[0][t] + part2[1][t] + part2[2][t] + part2[3][t];
    float mu = su * (1.f / CIN);
    float var = su2 * (1.f / CIN) - mu * mu;
    mu_s[t] = mu; isd_s[t] = rsqrtf(var + EPS_);
  }
  __syncthreads();
  if (t < CIN) {
    int c = ((t & 31) << 2) + (t >> 5);   // shuffled row -> orig channel
    smid[t] = (xs[c] - musd[0]) * musd[1] * g1[c] + b1[c];
  }
  {
    float mu = mu_s[l], isd = isd_s[l];
#pragma unroll
    for (int cc = 0; cc < 32; cc++) {
      int co = cc * 4 + q;
      tv[cc] = (tv[cc] - mu) * isd * g1[co] + b1[co];
    }
  }
  __syncthreads();
  float T2 = 0.f, T4 = 0.f, st = 0.f, sc2 = 0.f, S2 = 0.f, S4 = 0.f;
#pragma unroll
  for (int i = 0; i < 32; i++) {
    float si = smid[q * 32 + i];
    float ti = tv[i];
    float t2 = ti * ti;
    T2 += t2; T4 = fmaf(t2, t2, T4);
    float ci = si * ti;
    st += ci; sc2 = fmaf(ci, ci, sc2);
    float s2i = si * si;
    S2 += s2i; S4 = fmaf(s2i, s2i, S4);
  }
  float num = 0.5f * (st * st + sc2);
  float logit = num * rsqrtf(0.25f * (T2 * T2 + T4) * (S2 * S2 + S4));
  float e = expf(logit - 1.f);
  ws_a[((size_t)b * NH + q) * L_ + l0 + l] = e;
  float ws = e;
#pragma unroll
  for (int mk = 1; mk < 64; mk <<= 1) ws += __shfl_xor(ws, mk, 64);
  if (l == 0) ws_bsum[((size_t)b * NH + q) * 256 + (blk & 255)] = ws;
}

// ---------------- kernel 2: MFMA main — fp16 pk-mul P-build, 16 phases x 5 chunks ----------------
struct __align__(16) SmemM {
  union __align__(16) { unsigned short p2[4 * 5 * 4 * 16 * 8]; float zb[64 * 65]; } u1; // 20480 B
  unsigned short zn2[4 * 2 * 4 * 16 * 8];   // 8192 B
  float part[4][64], part2[4][64], mu_s[64], isd_s[64];
};

__global__ __launch_bounds__(256) void k_main(const float* __restrict__ x,
      const float* __restrict__ g1, const float* __restrict__ b1,
      const float* __restrict__ dr_b,
      const float* __restrict__ g2, const float* __restrict__ b2,
      const float* __restrict__ fc1_b,
      const unsigned short* __restrict__ wsw, const unsigned short* __restrict__ fsw,
      const float* __restrict__ ws_a, const float* __restrict__ ws_bsum,
      float* __restrict__ out) {
  __shared__ SmemM sm;
  int blk = blockIdx.x;
  int b = blk >> 8;
  int l0 = (blk & 255) << 6;
  int t = threadIdx.x;
  int l = t & 63, q = t >> 6;

  // asum: parallel 256-partial read + wave butterfly
  float asum;
  {
    const float* bs = ws_bsum + ((size_t)b * NH + q) * 256;
    float a0 = bs[l] + bs[l + 64] + bs[l + 128] + bs[l + 192];
#pragma unroll
    for (int mk = 1; mk < 64; mk <<= 1) a0 += __shfl_xor(a0, mk, 64);
    asum = a0;
  }
  float e = ws_a[((size_t)b * NH + q) * L_ + l0 + l];
  float sa = sqrtf(e * ((float)L_ / asum));

  // staging: thread (l,q) holds head q's 32 shuffled channels at position l0+l,
  // packed as 16 fp16-pair registers (shuffled row 32q+cc <-> orig channel cc*4+q).
  const float* xb = x + (size_t)b * CIN * L_ + l0 + l;
  h2 tnh[16];
  float s = 0.f, s2 = 0.f;
#pragma unroll
  for (int r = 0; r < 16; r++) {
    float v0 = xb[(size_t)((2 * r) * 4 + q) * L_];
    float v1 = xb[(size_t)((2 * r + 1) * 4 + q) * L_];
    s += v0 + v1; s2 += v0 * v0 + v1 * v1;
    tnh[r] = pkrtz(v0, v1);
  }
  sm.part[q][l] = s; sm.part2[q][l] = s2;
  __syncthreads();
  if (t < 64) {
    float su = sm.part[0][t] + sm.part[1][t] + sm.part[2][t] + sm.part[3][t];
    float su2 = sm.part2[0][t] + sm.part2[1][t] + sm.part2[2][t] + sm.part2[3][t];
    float mu = su * (1.f / CIN);
    float var = su2 * (1.f / CIN) - mu * mu;
    sm.mu_s[t] = mu; sm.isd_s[t] = rsqrtf(var + EPS_);
  }
  __syncthreads();
  {
    float mu = sm.mu_s[l], isd = sm.isd_s[l];
#pragma unroll
    for (int r = 0; r < 16; r++) {
      int c0 = (2 * r) * 4 + q, c1 = c0 + 4;
      float v0 = ((float)tnh[r][0] - mu) * isd * g1[c0] + b1[c0];
      float v1 = ((float)tnh[r][1] - mu) * isd * g1[c1] + b1[c1];
      v0 *= sa; v1 *= sa;
      tnh[r] = pkrtz(v0, v1);
    }
  }

  // main GEMM: wave q owns otile-pair (q&1) x ltile-pair (q>>1)
  const int otp = q & 1, ltp = q >> 1;
  const int lta = ltp * 2, ltb = ltp * 2 + 1;
  float4v acc[2][2];
  acc[0][0] = (float4v)0.f; acc[0][1] = (float4v)0.f;
  acc[1][0] = (float4v)0.f; acc[1][1] = (float4v)0.f;
  int tl = l;
  int ltile = l >> 4, n = l & 15;

  // 16 phases x 5 chunks; fully unrolled so all tnh[] indices are compile-time
#pragma unroll
  for (int p = 0; p < 16; p++) {
    // P-build: thread (l,q) builds its OWN head's blocks via packed fp16 muls.
#pragma unroll
    for (int ks = 0; ks < 5; ks++) {
      const int g = p * 5 + ks;            // global K-chunk == head-local k-block
      int i, jb; kb_decode(g, i, jb);
      _Float16 uh = tnh[i >> 1][i & 1];
      h2 uu = {uh, uh};
      h2 p0 = uu * tnh[jb * 4 + 0];
      h2 p1 = uu * tnh[jb * 4 + 1];
      h2 p2v = uu * tnh[jb * 4 + 2];
      h2 p3 = uu * tnh[jb * 4 + 3];
      uint4v pv = {__builtin_bit_cast(unsigned, p0), __builtin_bit_cast(unsigned, p1),
                   __builtin_bit_cast(unsigned, p2v), __builtin_bit_cast(unsigned, p3)};
      *(uint4v*)&sm.u1.p2[(((ltile * 5 + ks) * 4 + q) * 16 + n) * 8] = pv;
    }
    __syncthreads();
    // consume: 2 otiles x 2 ltiles per wave
#pragma unroll
    for (int ks = 0; ks < 5; ks++) {
      const unsigned short* wk = wsw + (size_t)(p * 5 + ks) * 2048 + otp * 1024 + tl * 8;
      half8 a0 = *(const half8*)(wk);
      half8 a1 = *(const half8*)(wk + 512);
      half8 b0 = *(half8*)&sm.u1.p2[((lta * 5 + ks) * 64 + tl) * 8];
      half8 b1v = *(half8*)&sm.u1.p2[((ltb * 5 + ks) * 64 + tl) * 8];
      acc[0][0] = __builtin_amdgcn_mfma_f32_16x16x32_f16(a0, b0,  acc[0][0], 0, 0, 0);
      acc[0][1] = __builtin_amdgcn_mfma_f32_16x16x32_f16(a0, b1v, acc[0][1], 0, 0, 0);
      acc[1][0] = __builtin_amdgcn_mfma_f32_16x16x32_f16(a1, b0,  acc[1][0], 0, 0, 0);
      acc[1][1] = __builtin_amdgcn_mfma_f32_16x16x32_f16(a1, b1v, acc[1][1], 0, 0, 0);
    }
    __syncthreads();
  }

  // epilogue: z -> zb (2x2 mapping), norm2, zn2 frags, fc1 MFMA, GELU
  int quad = tl >> 4;
#pragma unroll
  for (int oi = 0; oi < 2; oi++) {
#pragma unroll
    for (int li = 0; li < 2; li++) {
      int ot = otp * 2 + oi, ltx = ltp * 2 + li;
#pragma unroll
      for (int r = 0; r < 4; r++) {
        int o = ot * 16 + quad * 4 + r;
        sm.u1.zb[(ltx * 16 + n) * 65 + o] = acc[oi][li][r] + dr_b[o];
      }
    }
  }
  __syncthreads();
  {
    float ss = 0.f, ss2 = 0.f;
#pragma unroll
    for (int k = 0; k < 16; k++) {
      float v = sm.u1.zb[l * 65 + q * 16 + k];
      ss += v; ss2 += v * v;
    }
    sm.part[q][l] = ss; sm.part2[q][l] = ss2;
  }
  __syncthreads();
  if (t < 64) {
    float su = sm.part[0][t] + sm.part[1][t] + sm.part[2][t] + sm.part[3][t];
    float su2 = sm.part2[0][t] + sm.part2[1][t] + sm.part2[2][t] + sm.part2[3][t];
    float mu = su * (1.f / DIM_);
    float var = su2 * (1.f / DIM_) - mu * mu;
    sm.mu_s[t] = mu; sm.isd_s[t] = rsqrtf(var + EPS_);
  }
  __syncthreads();
  {
    float mu2 = sm.mu_s[l], isd2 = sm.isd_s[l];
#pragma unroll
    for (int kk = 0; kk < 2; kk++) {
      int kb2 = q * 2 + kk;
      int c0 = kb2 * 8;
      unsigned short pk[8];
#pragma unroll
      for (int e8 = 0; e8 < 8; e8++) {
        int c = c0 + e8;
        float v = (sm.u1.zb[l * 65 + c] - mu2) * isd2 * g2[c] + b2[c];
        pk[e8] = f2h(v);
      }
      int ks2 = kb2 >> 2, qd2 = kb2 & 3;
      *(short8*)&sm.zn2[(((ltile * 2 + ks2) * 4 + qd2) * 16 + n) * 8] = *(short8*)pk;
    }
  }
  __syncthreads();
  float4v acc2[4];
  acc2[0] = (float4v)0.f; acc2[1] = (float4v)0.f; acc2[2] = (float4v)0.f; acc2[3] = (float4v)0.f;
#pragma unroll
  for (int ks2 = 0; ks2 < 2; ks2++) {
    half8 bz = *(half8*)&sm.zn2[((q * 2 + ks2) * 64 + tl) * 8];
    const unsigned short* fk = fsw + ks2 * 2048 + tl * 8;
    half8 f0 = *(const half8*)(fk);
    half8 f1 = *(const half8*)(fk + 512);
    half8 f2 = *(const half8*)(fk + 1024);
    half8 f3 = *(const half8*)(fk + 1536);
    acc2[0] = __builtin_amdgcn_mfma_f32_16x16x32_f16(f0, bz, acc2[0], 0, 0, 0);
    acc2[1] = __builtin_amdgcn_mfma_f32_16x16x32_f16(f1, bz, acc2[1], 0, 0, 0);
    acc2[2] = __builtin_amdgcn_mfma_f32_16x16x32_f16(f2, bz, acc2[2], 0, 0, 0);
    acc2[3] = __builtin_amdgcn_mfma_f32_16x16x32_f16(f3, bz, acc2[3], 0, 0, 0);
  }
#pragma unroll
  for (int ot = 0; ot < 4; ot++) {
#pragma unroll
    for (int r = 0; r < 4; r++) {
      int o2 = ot * 16 + quad * 4 + r;
      float sv = acc2[ot][r] + fc1_b[o2];
      float g = 0.5f * sv * (1.f + erff(sv * 0.70710678118f));
      out[((size_t)b * DIM_ + o2) * L_ + l0 + q * 16 + n] = g;
    }
  }
}

extern "C" void kernel_launch(void* const* d_in, const int* in_sizes, int n_in,
                              void* d_out, int out_size, void* d_ws, size_t ws_size,
                              hipStream_t stream) {
  const float* x    = (const float*)d_in[0];
  const float* n1w  = (const float*)d_in[1];
  const float* n1b  = (const float*)d_in[2];
  const float* drw  = (const float*)d_in[3];
  const float* drb  = (const float*)d_in[4];
  const float* n2w  = (const float*)d_in[5];
  const float* n2b  = (const float*)d_in[6];
  const float* fc1w = (const float*)d_in[7];
  const float* fc1b = (const float*)d_in[8];
  float* out = (float*)d_out;
  float* ws = (float*)d_ws;
  float* ws_a    = ws;                                  // 4*4*16384 floats
  float* ws_bsum = ws_a + (size_t)B_ * NH * L_;         // 16*256 floats
  unsigned short* wsw = (unsigned short*)(ws_bsum + B_ * NH * 256); // 163840 fp16
  unsigned short* fsw = wsw + WSWN;                     // 4096 fp16

  hipLaunchKernelGGL(k_pre, dim3(LOGITS_BLOCKS + PREP_BLOCKS), dim3(256), 0, stream,
                     drw, fc1w, x, n1w, n1b, wsw, fsw, ws_a, ws_bsum);
  hipLaunchKernelGGL(k_main, dim3(B_ * (L_ / LT)), dim3(256), 0, stream,
                     x, n1w, n1b, drb, n2w, n2b, fc1b, wsw, fsw, ws_a, ws_bsum, out);
}